// Round 7
// baseline (289.808 us; speedup 1.0000x reference)
//
#include <hip/hip_runtime.h>
#include <hip/hip_bf16.h>

// Problem constants: B,T,V,E,U = 256,512,20000,128,128
#define BB 256
#define TT 512
#define VV 20000
#define EE 128
#define UU 128
#define G4 512   // 4*U gate width

typedef _Float16 f16x8 __attribute__((ext_vector_type(8)));
typedef float    f32x4 __attribute__((ext_vector_type(4)));

// Fast device math: error ~1e-6, vastly under the 1e-2 absmax threshold.
__device__ __forceinline__ float sigmoid_f(float x) {
    float e = __expf(-x);
    return __builtin_amdgcn_rcpf(1.0f + e);
}
__device__ __forceinline__ float tanh_f(float x) {
    float e = __expf(2.0f * x);
    return 1.0f - 2.0f * __builtin_amdgcn_rcpf(e + 1.0f);
}

// ---------------------------------------------------------------------------
// Phase 1: projected-token table in GATE-MINOR layout:
//   P2[v][u][g] = sum_e emb[v][e]*K[e][g*128+u] + bias[g*128+u]
// so the lstm kernel fetches one float4 (all 4 gates of a unit) per lane.
// tid -> (g = tid&3, u = tid>>2) makes the P2 store fully coalesced.
// ---------------------------------------------------------------------------
__global__ __launch_bounds__(512, 2) void proj_kernel(
    const float* __restrict__ emb, const float* __restrict__ wk,
    const float* __restrict__ bias, float* __restrict__ P2) {
    const int tid = threadIdx.x;
    const int g   = tid & 3;
    const int u   = tid >> 2;
    const int col = g * 128 + u;          // original gate-column
    const int v0  = blockIdx.x * 16;

    __shared__ float elds[16 * EE];
    ((float4*)elds)[tid] = ((const float4*)(emb + (size_t)v0 * EE))[tid];
    __syncthreads();

    float bcol = bias[col];
    float acc[16];
#pragma unroll
    for (int r = 0; r < 16; ++r) acc[r] = bcol;

    const float4* elds4 = (const float4*)elds;
    for (int e0 = 0; e0 < EE; e0 += 4) {
        // per fixed e: lanes read cols (tid&3)*128 + (tid>>2) -> four 64B
        // contiguous segments per wave: acceptable for an L2-resident wk.
        float k0 = wk[(e0 + 0) * G4 + col];
        float k1 = wk[(e0 + 1) * G4 + col];
        float k2 = wk[(e0 + 2) * G4 + col];
        float k3 = wk[(e0 + 3) * G4 + col];
#pragma unroll
        for (int r = 0; r < 16; ++r) {
            float4 ev = elds4[r * 32 + (e0 >> 2)];
            acc[r] = fmaf(ev.x, k0, acc[r]);
            acc[r] = fmaf(ev.y, k1, acc[r]);
            acc[r] = fmaf(ev.z, k2, acc[r]);
            acc[r] = fmaf(ev.w, k3, acc[r]);
        }
    }
#pragma unroll
    for (int r = 0; r < 16; ++r)
        P2[(size_t)(v0 + r) * G4 + tid] = acc[r];   // [v][u][g], coalesced
}

// ---------------------------------------------------------------------------
// Phase 2: sequential LSTM via MFMA. Key insight used this round: the MFMA
// D-layout (col=lane&15, rows replicated) means EVERY lane already holds
// z for all 4 gates of its unit in acc[g][0] -> no kq-select, no shuffles;
// each lane runs the full i,f,g,o + (c,h) update redundantly (x4 across kq
// groups). 8 accumulators (depth-2 chains) halve dependent-MFMA latency.
// P fetched as one dwordx4/lane/step from the gate-minor P2 table with the
// depth-4 in-flight pipeline (statically indexed pf4[4], counted vmcnt).
// Raw s_barrier + lgkmcnt(0)-only drain; global loads cross the barrier.
// ---------------------------------------------------------------------------
__global__ __launch_bounds__(512, 2) void lstm_kernel(
    const int* __restrict__ tokens, const float* __restrict__ rk,
    const float* __restrict__ P2, const float* __restrict__ dense_w,
    const float* __restrict__ dense_b, float* __restrict__ out) {
    const int tid = threadIdx.x;
    const int w   = tid >> 6;       // wave 0..7
    const int l   = tid & 63;       // lane
    const int j   = l & 15;         // unit index within the wave's 16
    const int kq  = l >> 4;         // k-quarter (fragment row group)
    const int b   = blockIdx.x;
    const int ucol = 16 * w + j;    // unit column

    __shared__ __align__(16) _Float16 hbuf[2][UU];  // double-buffered h
    __shared__ int   tokLDS[TT];                    // whole token row (2 KB)
    __shared__ float red[8];

    // ---- B-fragments: bf[kt][g][i] = rk[32kt+8kq+i][g*128 + ucol] (f16) ----
    f16x8 bf[4][4];
#pragma unroll
    for (int kt = 0; kt < 4; ++kt) {
#pragma unroll
        for (int g = 0; g < 4; ++g) {
            f16x8 v;
#pragma unroll
            for (int i = 0; i < 8; ++i) {
                v[i] = (_Float16)rk[(size_t)(32 * kt + 8 * kq + i) * G4
                                    + g * 128 + ucol];
            }
            bf[kt][g] = v;
        }
    }

    const int* trow = tokens + (size_t)b * TT;
    tokLDS[tid] = trow[tid];                 // 512 threads = 512 tokens
    if (tid < UU) hbuf[0][tid] = (_Float16)0.f;   // h0 = 0
    float c_state = 0.f, hv = 0.f;

    // this lane's P2 pointer: all 4 gates of unit ucol, 16B aligned
    const float4* Pc4 = (const float4*)(P2 + (size_t)ucol * 4);
    // depth-4 prologue: P for t = 0..3 (one dwordx4 each)
    float4 pf[4];
#pragma unroll
    for (int s = 0; s < 4; ++s) pf[s] = Pc4[(size_t)trow[s] * 128];
    __syncthreads();

    const f32x4 cz = {0.f, 0.f, 0.f, 0.f};

    for (int t = 0; t < TT; t += 4) {
#pragma unroll
        for (int s = 0; s < 4; ++s) {
            // --- token for t+s+4 (LDS, hot) ---
            int tki  = t + s + 4; if (tki > TT - 1) tki = TT - 1;
            int vtok = tokLDS[tki];

            // --- A-fragments: h broadcast slices from LDS ---
            f16x8 af[4];
#pragma unroll
            for (int kt = 0; kt < 4; ++kt)
                af[kt] = *(const f16x8*)&hbuf[s & 1][32 * kt + 8 * kq];

            // --- issue P prefetch for t+s+4 early (flies over the MFMAs) ---
            float4 pnew = Pc4[(size_t)vtok * 128];

            // --- z = h @ R : 8 independent chains (depth 2), 16 MFMA ---
            f32x4 accA[4], accB[4];
#pragma unroll
            for (int g = 0; g < 4; ++g) {
                accA[g] = __builtin_amdgcn_mfma_f32_16x16x32_f16(af[0], bf[0][g], cz, 0, 0, 0);
                accB[g] = __builtin_amdgcn_mfma_f32_16x16x32_f16(af[2], bf[2][g], cz, 0, 0, 0);
            }
#pragma unroll
            for (int g = 0; g < 4; ++g) {
                accA[g] = __builtin_amdgcn_mfma_f32_16x16x32_f16(af[1], bf[1][g], accA[g], 0, 0, 0);
                accB[g] = __builtin_amdgcn_mfma_f32_16x16x32_f16(af[3], bf[3][g], accB[g], 0, 0, 0);
            }

            // --- every lane holds z for all 4 gates of unit ucol ---
            float z0 = accA[0][0] + accB[0][0] + pf[s].x;
            float z1 = accA[1][0] + accB[1][0] + pf[s].y;
            float z2 = accA[2][0] + accB[2][0] + pf[s].z;
            float z3 = accA[3][0] + accB[3][0] + pf[s].w;

            // --- full gate set in-lane (4 independent trans chains) ---
            float gi = sigmoid_f(z0);
            float gf = sigmoid_f(z1);
            float gg = tanh_f(z2);
            float go = sigmoid_f(z3);
            c_state = fmaf(gf, c_state, gi * gg);
            hv      = go * tanh_f(c_state);

            if (kq == 0) hbuf[(s + 1) & 1][ucol] = (_Float16)hv;  // publish h
            pf[s] = pnew;

            // LDS-only drain + raw barrier: P loads survive across steps
            asm volatile("s_waitcnt lgkmcnt(0)" ::: "memory");
            __builtin_amdgcn_s_barrier();
        }
    }

    // --- dense sigmoid head: out[b] = sigmoid(h @ w + b) ---
    float val = (kq == 0) ? hv * dense_w[ucol] : 0.f;
#pragma unroll
    for (int off = 32; off > 0; off >>= 1) val += __shfl_xor(val, off, 64);
    if (l == 0) red[w] = val;
    __syncthreads();
    if (tid == 0) {
        float sum = dense_b[0];
#pragma unroll
        for (int i = 0; i < 8; ++i) sum += red[i];
        out[b] = sigmoid_f(sum);
    }
}

extern "C" void kernel_launch(void* const* d_in, const int* in_sizes, int n_in,
                              void* d_out, int out_size, void* d_ws, size_t ws_size,
                              hipStream_t stream) {
    const int*   tokens = (const int*)  d_in[0];
    const float* emb    = (const float*)d_in[1];
    const float* wk     = (const float*)d_in[2];
    const float* rk     = (const float*)d_in[3];
    const float* bias   = (const float*)d_in[4];
    const float* dw     = (const float*)d_in[5];
    const float* db     = (const float*)d_in[6];
    float* out = (float*)d_out;
    float* P2  = (float*)d_ws;     // 20000*512*4 = 40.96 MB scratch

    proj_kernel<<<VV / 16, 512, 0, stream>>>(emb, wk, bias, P2);
    lstm_kernel<<<BB, 512, 0, stream>>>(tokens, rk, P2, dw, db, out);
}